// Round 10
// baseline (421.435 us; speedup 1.0000x reference)
//
#include <hip/hip_runtime.h>
#include <hip/hip_bf16.h>
#include <cstdint>
#include <cstddef>
#include <cstring>

#define B_ 2
#define T_ 2048
#define C_ 1024
#define H_ 16
#define HD_ 64
#define FF_ 4096
#define BT_ (B_*T_)   // 4096 rows

typedef __attribute__((ext_vector_type(8))) short short8;
typedef __attribute__((ext_vector_type(4))) float f32x4;

__device__ __forceinline__ float bf2f(ushort u) {
    return __uint_as_float(((uint)u) << 16);
}
__device__ __forceinline__ ushort f2bf(float f) {
    uint x = __float_as_uint(f);
    return (ushort)((x + 0x7fffu + ((x >> 16) & 1u)) >> 16);
}
// hot-path convert: scalar cast so compiler can fuse v_cvt_pk_bf16_f32 (m240)
__device__ __forceinline__ ushort f2bf_hw(float f) {
    __hip_bfloat16 h = __float2bfloat16(f);
    ushort u;
    __builtin_memcpy(&u, &h, 2);
    return u;
}

#define GLDS16(g, l)                                                        \
    __builtin_amdgcn_global_load_lds(                                       \
        (const __attribute__((address_space(1))) void*)(g),                 \
        (__attribute__((address_space(3))) void*)(l), 16, 0, 0)

// ---------------------------------------------------------------------------
// LayerNorm: one block (256 threads) per row of C_=1024, fp32 in, bf16 out.
// ---------------------------------------------------------------------------
__global__ __launch_bounds__(256) void ln_kernel(const float* __restrict__ x,
                                                 const float* __restrict__ g,
                                                 const float* __restrict__ b,
                                                 ushort* __restrict__ out) {
    int row = blockIdx.x;
    int tid = threadIdx.x;
    const float* xr = x + (size_t)row * C_;
    float4 v = *(const float4*)(xr + tid * 4);
    float s = v.x + v.y + v.z + v.w;
    float q = v.x*v.x + v.y*v.y + v.z*v.z + v.w*v.w;
    #pragma unroll
    for (int off = 32; off > 0; off >>= 1) {
        s += __shfl_down(s, off);
        q += __shfl_down(q, off);
    }
    __shared__ float ss[4], qs[4];
    if ((tid & 63) == 0) { ss[tid >> 6] = s; qs[tid >> 6] = q; }
    __syncthreads();
    s = ss[0] + ss[1] + ss[2] + ss[3];
    q = qs[0] + qs[1] + qs[2] + qs[3];
    float mu  = s * (1.0f / C_);
    float var = q * (1.0f / C_) - mu * mu;
    float r = rsqrtf(var + 1e-5f);
    float4 gv = *(const float4*)(g + tid * 4);
    float4 bv = *(const float4*)(b + tid * 4);
    ushort4 o;
    o.x = f2bf((v.x - mu) * r * gv.x + bv.x);
    o.y = f2bf((v.y - mu) * r * gv.y + bv.y);
    o.z = f2bf((v.z - mu) * r * gv.z + bv.z);
    o.w = f2bf((v.w - mu) * r * gv.w + bv.w);
    *(ushort4*)(out + (size_t)row * C_ + tid * 4) = o;
}

// ---------------------------------------------------------------------------
// Tiled transpose + fp32->bf16 convert. (weights, once per call)
// ---------------------------------------------------------------------------
__global__ __launch_bounds__(256) void tcvt_kernel(const float* __restrict__ in,
                                                   ushort* __restrict__ out,
                                                   int R, int Cc, int ldo,
                                                   long in_bs, long out_bs) {
    __shared__ float tile[32][33];
    const float* inz = in + (size_t)blockIdx.z * in_bs;
    ushort* outz = out + (size_t)blockIdx.z * out_bs;
    int c0 = blockIdx.x * 32, r0 = blockIdx.y * 32;
    #pragma unroll
    for (int i = 0; i < 4; i++) {
        int r = threadIdx.y + i * 8;
        tile[r][threadIdx.x] = inz[(size_t)(r0 + r) * Cc + c0 + threadIdx.x];
    }
    __syncthreads();
    #pragma unroll
    for (int i = 0; i < 4; i++) {
        int c = threadIdx.y + i * 8;
        outz[(size_t)(c0 + c) * ldo + r0 + threadIdx.x] = f2bf(tile[threadIdx.x][c]);
    }
}

// ---------------------------------------------------------------------------
// bf16 MFMA GEMM, phase-structured (T2+T3+T4+T5+T1):
// BM=128 x BN=256, BK=64, 512 thr = 8 waves. (unchanged from round 7)
// ---------------------------------------------------------------------------
template<int EPI, bool OUT_BF16>
__global__ __launch_bounds__(512, 2) void gemm2(
    const ushort* __restrict__ A,
    const ushort* __restrict__ Bt,
    void* __restrict__ Cout,
    const float* __restrict__ bias,
    const float* __restrict__ resid,
    int M, int N, int K, int KS)
{
    __shared__ ushort As[2][128 * 64];   // 2 x 16 KB
    __shared__ ushort Bs[2][256 * 64];   // 2 x 32 KB

    int gx = gridDim.x;
    int nwg = gx * gridDim.y;
    int bid = blockIdx.y * gx + blockIdx.x;
    int cpx = nwg >> 3;
    int swz = (bid & 7) * cpx + (bid >> 3);
    int bx = swz % gx, by = swz / gx;

    int tid  = threadIdx.x;
    int lane = tid & 63;
    int lr = lane & 15, lq = lane >> 4;
    int wave = tid >> 6;                 // 0..7
    int wr = wave >> 2, wc = wave & 3;
    int m0 = by * 128, n0 = bx * 256;
    int Koff = blockIdx.z * KS;
    size_t zoff = (size_t)blockIdx.z * ((size_t)M * N);

    f32x4 acc[4][4];
    #pragma unroll
    for (int i = 0; i < 4; i++)
        #pragma unroll
        for (int j = 0; j < 4; j++)
            acc[i][j] = {0.f, 0.f, 0.f, 0.f};

    int srow = tid >> 3;
    int scol = ((tid & 7) ^ (srow & 7)) * 8;
    const ushort* gA = A  + (size_t)(m0 + srow) * K + Koff + scol;
    const ushort* gB = Bt + (size_t)(n0 + srow) * K + Koff + scol;
    int NT = KS / 64;

    auto stage = [&](int kt, int buf) {
        const ushort* a = gA + kt * 64;
        const ushort* b = gB + kt * 64;
        char* la = (char*)As[buf] + wave * 1024;
        char* lb = (char*)Bs[buf] + wave * 1024;
        GLDS16(a, la);
        GLDS16(a + (size_t)64 * K, la + 8192);
        #pragma unroll
        for (int i = 0; i < 4; i++)
            GLDS16(b + (size_t)i * 64 * K, lb + i * 8192);
    };

    stage(0, 0);
    stage(1, 1);
    asm volatile("s_waitcnt vmcnt(6)" ::: "memory");
    __builtin_amdgcn_s_barrier();

    int sx4 = (lr & 7) << 4;
    int so0 = (lq << 4) ^ sx4;
    int so1 = ((4 + lq) << 4) ^ sx4;

    int cur = 0;
    for (int t = 0; t < NT; ++t) {
        const char* Ab = (const char*)As[cur] + (wr * 64 + lr) * 128;
        const char* Bb = (const char*)Bs[cur] + (wc * 64 + lr) * 128;

        short8 bf[4][2], af[2][2];
        #pragma unroll
        for (int fc = 0; fc < 4; fc++) {
            bf[fc][0] = *(const short8*)(Bb + fc * 2048 + so0);
            bf[fc][1] = *(const short8*)(Bb + fc * 2048 + so1);
        }
        #pragma unroll
        for (int r = 0; r < 2; r++) {
            af[r][0] = *(const short8*)(Ab + r * 2048 + so0);
            af[r][1] = *(const short8*)(Ab + r * 2048 + so1);
        }
        __builtin_amdgcn_s_barrier();
        __builtin_amdgcn_s_setprio(1);
        #pragma unroll
        for (int r = 0; r < 2; r++)
            #pragma unroll
            for (int fc = 0; fc < 4; fc++) {
                acc[r][fc] = __builtin_amdgcn_mfma_f32_16x16x32_bf16(
                    af[r][0], bf[fc][0], acc[r][fc], 0, 0, 0);
                acc[r][fc] = __builtin_amdgcn_mfma_f32_16x16x32_bf16(
                    af[r][1], bf[fc][1], acc[r][fc], 0, 0, 0);
            }
        __builtin_amdgcn_s_setprio(0);
        __builtin_amdgcn_s_barrier();

        #pragma unroll
        for (int r = 0; r < 2; r++) {
            af[r][0] = *(const short8*)(Ab + (2 + r) * 2048 + so0);
            af[r][1] = *(const short8*)(Ab + (2 + r) * 2048 + so1);
        }
        __builtin_amdgcn_s_barrier();
        __builtin_amdgcn_s_setprio(1);
        #pragma unroll
        for (int r = 0; r < 2; r++)
            #pragma unroll
            for (int fc = 0; fc < 4; fc++) {
                acc[2 + r][fc] = __builtin_amdgcn_mfma_f32_16x16x32_bf16(
                    af[r][0], bf[fc][0], acc[2 + r][fc], 0, 0, 0);
                acc[2 + r][fc] = __builtin_amdgcn_mfma_f32_16x16x32_bf16(
                    af[r][1], bf[fc][1], acc[2 + r][fc], 0, 0, 0);
            }
        __builtin_amdgcn_s_setprio(0);
        __builtin_amdgcn_s_barrier();

        if (t + 1 == NT) break;
        if (t + 2 < NT) {
            stage(t + 2, cur);
            asm volatile("s_waitcnt vmcnt(6)" ::: "memory");
        } else {
            asm volatile("s_waitcnt vmcnt(0)" ::: "memory");
        }
        __builtin_amdgcn_s_barrier();
        cur ^= 1;
    }

    #pragma unroll
    for (int fr = 0; fr < 4; fr++) {
        #pragma unroll
        for (int fc = 0; fc < 4; fc++) {
            int col = n0 + wc * 64 + fc * 16 + lr;
            #pragma unroll
            for (int j = 0; j < 4; j++) {
                int row = m0 + wr * 64 + fr * 16 + lq * 4 + j;
                float v = acc[fr][fc][j];
                if (EPI & 1) v += bias[col];
                if (EPI & 2) v = fmaxf(v, 0.f);
                if (EPI & 4) v += resid[(size_t)row * N + col];
                if (OUT_BF16)
                    ((ushort*)Cout)[zoff + (size_t)row * N + col] = f2bf(v);
                else
                    ((float*)Cout)[zoff + (size_t)row * N + col] = v;
            }
        }
    }
}

// ---------------------------------------------------------------------------
// FF2 split-K finalize: out += p0 + p1 + b2   (p bf16 partials, out fp32)
// ---------------------------------------------------------------------------
__global__ __launch_bounds__(256) void ff2_red(float* __restrict__ out,
                                               const ushort* __restrict__ p,
                                               const float* __restrict__ b2) {
    size_t i = (size_t)blockIdx.x * 256 + threadIdx.x;   // 4-elem groups
    float4 o = ((float4*)out)[i];
    ushort4 a = ((const ushort4*)p)[i];
    ushort4 b = ((const ushort4*)(p + (size_t)BT_ * C_))[i];
    float4 c = ((const float4*)b2)[i & 255];
    o.x += bf2f(a.x) + bf2f(b.x) + c.x;
    o.y += bf2f(a.y) + bf2f(b.y) + c.y;
    o.z += bf2f(a.z) + bf2f(b.z) + c.z;
    o.w += bf2f(a.w) + bf2f(b.w) + c.w;
    ((float4*)out)[i] = o;
}

// ---------------------------------------------------------------------------
// MFMA causal flash attention, DIRECT-FROM-GLOBAL K/V (no LDS staging, no
// block barriers): K/V per head is L2-resident (2 x 256 KB) and shared by
// the 4 waves of a block via L1 — staging was pure overhead (mistake #7).
// Each wave: K frags -> regs (8 x dwordx4), QK^T MFMA, online softmax,
// P -> per-wave swizzled LDS (lgkmcnt-ordered, barrier-free), V frags ->
// regs, PV MFMA. KV-parity split z over 64-key tiles; combine pass merges.
// qk : [BT_][2048] bf16 (q at h*64, k at 1024+h*64)
// vt : [1024][4096] bf16 = V^T;  Opart: [2][BT_][1024] bf16
// ml : [2][H][BT_][2] fp32  (m2 log2-domain, l)
// ---------------------------------------------------------------------------
__global__ __launch_bounds__(256, 3) void attn_mfma(const ushort* __restrict__ qk,
                                                    const ushort* __restrict__ vt,
                                                    ushort* __restrict__ Opart,
                                                    float* __restrict__ ml) {
    const float C2 = 0.18033688011f;     // 0.125 * log2(e)
    const float THR2 = 12.0f;            // defer-max threshold (log2 domain)

    int bh = blockIdx.y;
    int bb = bh >> 4;
    int head = bh & 15;
    int qa = 15 - blockIdx.x;            // heavy tiles first
    int q0 = qa * 128;
    int z = blockIdx.z;

    int tid  = threadIdx.x;
    int lane = tid & 63;
    int lr = lane & 15, lq = lane >> 4;
    int wave = tid >> 6;
    int qw = q0 + wave * 32;

    __shared__ ushort Ps[4][32 * 64];    // 16 KB total; per-wave 4 KB
    char* pw = (char*)Ps[wave];

    // Q fragments (held in registers the whole kernel)
    short8 qf[2][2];
    {
        const ushort* qb = qk + ((size_t)(bb * T_ + qw)) * 2048 + head * 64;
        #pragma unroll
        for (int mt = 0; mt < 2; mt++)
            #pragma unroll
            for (int kk = 0; kk < 2; kk++)
                qf[mt][kk] = *(const short8*)(qb + (size_t)(mt*16 + lr) * 2048 + kk*32 + lq*8);
    }

    f32x4 acc[2][4];
    f32x4 lsum[2];
    float m2[2][4];
    #pragma unroll
    for (int mt = 0; mt < 2; mt++) {
        #pragma unroll
        for (int dt = 0; dt < 4; dt++) acc[mt][dt] = {0.f, 0.f, 0.f, 0.f};
        lsum[mt] = {0.f, 0.f, 0.f, 0.f};
        #pragma unroll
        for (int j = 0; j < 4; j++) m2[mt][j] = -INFINITY;
    }

    const short8 onesf = {(short)0x3F80, (short)0x3F80, (short)0x3F80, (short)0x3F80,
                          (short)0x3F80, (short)0x3F80, (short)0x3F80, (short)0x3F80};

    // per-lane fragment bases (K rows = keys; V^T rows = d)
    const ushort* kb0 = qk + (size_t)bb * T_ * 2048 + 1024 + head * 64
                      + (size_t)lr * 2048 + lq * 8;
    const ushort* vb0 = vt + ((size_t)(head * 64 + lr)) * 4096 + (size_t)bb * T_
                      + lq * 8;

    // 64-key tiles of parity z (even/odd), causal bound per wave
    for (int s0h = z * 64; s0h <= qw + 31; s0h += 128) {
        // ---- K fragments -> regs (8 global dwordx4, issued together) ----
        short8 kf[4][2];
        #pragma unroll
        for (int n = 0; n < 4; n++)
            #pragma unroll
            for (int kk = 0; kk < 2; kk++)
                kf[n][kk] = *(const short8*)(kb0 + (size_t)(s0h + n*16) * 2048 + kk*32);

        // ---- S = Q K^T ----
        f32x4 sa[2][4];
        __builtin_amdgcn_s_setprio(1);
        #pragma unroll
        for (int n = 0; n < 4; n++)
            #pragma unroll
            for (int mt = 0; mt < 2; mt++) {
                f32x4 tq = {0.f, 0.f, 0.f, 0.f};
                tq = __builtin_amdgcn_mfma_f32_16x16x32_bf16(qf[mt][0], kf[n][0], tq, 0, 0, 0);
                tq = __builtin_amdgcn_mfma_f32_16x16x32_bf16(qf[mt][1], kf[n][1], tq, 0, 0, 0);
                sa[mt][n] = tq;
            }
        __builtin_amdgcn_s_setprio(0);

        // ---- causal mask (diagonal tile only; wave-uniform branch) ----
        if (s0h + 63 > qw) {
            #pragma unroll
            for (int mt = 0; mt < 2; mt++)
                #pragma unroll
                for (int n = 0; n < 4; n++)
                    #pragma unroll
                    for (int j = 0; j < 4; j++) {
                        int scolm = s0h + n*16 + lr;
                        int qrow = qw + mt*16 + lq*4 + j;
                        if (scolm > qrow) sa[mt][n][j] = -INFINITY;
                    }
        }

        // ---- row maxes (log2-scaled) + defer-max vote ----
        float vmax2[2][4];
        bool growf = false;
        #pragma unroll
        for (int mt = 0; mt < 2; mt++) {
            #pragma unroll
            for (int j = 0; j < 4; j++) {
                float v = fmaxf(fmaxf(sa[mt][0][j], sa[mt][1][j]),
                                fmaxf(sa[mt][2][j], sa[mt][3][j]));
                #pragma unroll
                for (int off = 1; off < 16; off <<= 1)
                    v = fmaxf(v, __shfl_xor(v, off));
                float v2 = v * C2;
                vmax2[mt][j] = v2;
                growf |= (v2 > m2[mt][j] + THR2);
            }
        }
        if (__any(growf)) {
            #pragma unroll
            for (int mt = 0; mt < 2; mt++)
                #pragma unroll
                for (int j = 0; j < 4; j++) {
                    float m2n = fmaxf(m2[mt][j], vmax2[mt][j]);
                    float corr = __builtin_amdgcn_exp2f(m2[mt][j] - m2n);
                    m2[mt][j] = m2n;
                    lsum[mt][j] *= corr;
                    #pragma unroll
                    for (int dt = 0; dt < 4; dt++)
                        acc[mt][dt][j] *= corr;
                }
        }

        // ---- P = exp2(s*C2 - m2) -> bf16 -> per-wave swizzled LDS ----
        #pragma unroll
        for (int mt = 0; mt < 2; mt++)
            #pragma unroll
            for (int n = 0; n < 4; n++)
                #pragma unroll
                for (int j = 0; j < 4; j++) {
                    float p = __builtin_amdgcn_exp2f(
                        fmaf(sa[mt][n][j], C2, -m2[mt][j]));
                    int row = mt*16 + lq*4 + j;
                    int col = n*16 + lr;
                    int byte = row*128 + ((((col >> 3) ^ (row & 7))) << 4) + (col & 7)*2;
                    *(ushort*)(pw + byte) = f2bf_hw(p);
                }

        // ---- read P fragments (same-wave lgkmcnt ordering, no barrier) ----
        short8 pf[2][2];
        #pragma unroll
        for (int mt = 0; mt < 2; mt++) {
            int row = mt*16 + lr;
            #pragma unroll
            for (int kk = 0; kk < 2; kk++)
                pf[mt][kk] = *(const short8*)(pw + row*128
                               + (((kk*4 + lq) ^ (row & 7)) << 4));
        }

        // ---- V fragments -> regs; lsum += P*1; O += P V ----
        short8 vf[4][2];
        #pragma unroll
        for (int dt = 0; dt < 4; dt++)
            #pragma unroll
            for (int kk = 0; kk < 2; kk++)
                vf[dt][kk] = *(const short8*)(vb0 + (size_t)(dt*16) * 4096
                               + s0h + kk*32);

        __builtin_amdgcn_s_setprio(1);
        #pragma unroll
        for (int kk = 0; kk < 2; kk++)
            #pragma unroll
            for (int mt = 0; mt < 2; mt++)
                lsum[mt] = __builtin_amdgcn_mfma_f32_16x16x32_bf16(
                    pf[mt][kk], onesf, lsum[mt], 0, 0, 0);
        #pragma unroll
        for (int dt = 0; dt < 4; dt++)
            #pragma unroll
            for (int kk = 0; kk < 2; kk++)
                #pragma unroll
                for (int mt = 0; mt < 2; mt++)
                    acc[mt][dt] = __builtin_amdgcn_mfma_f32_16x16x32_bf16(
                        pf[mt][kk], vf[dt][kk], acc[mt][dt], 0, 0, 0);
        __builtin_amdgcn_s_setprio(0);
    }

    // ---- epilogue: normalized partial O -> Opart[z]; (m2,l) -> ml ----
    ushort* ob = Opart + (size_t)z * ((size_t)BT_ * C_)
               + ((size_t)(bb * T_ + qw)) * 1024 + head * 64;
    #pragma unroll
    for (int mt = 0; mt < 2; mt++)
        #pragma unroll
        for (int j = 0; j < 4; j++) {
            float l = lsum[mt][j];
            float inv = l > 0.f ? 1.0f / l : 0.f;
            #pragma unroll
            for (int dt = 0; dt < 4; dt++)
                ob[(size_t)(mt*16 + lq*4 + j) * 1024 + dt*16 + lr] =
                    f2bf(acc[mt][dt][j] * inv);
        }
    if (lr == 0) {
        float* mlz = ml + ((size_t)(z * 16 + head)) * (BT_ * 2);
        #pragma unroll
        for (int mt = 0; mt < 2; mt++)
            #pragma unroll
            for (int j = 0; j < 4; j++) {
                size_t row = (size_t)(bb * T_ + qw + mt*16 + lq*4 + j);
                *(float2*)(mlz + row * 2) = make_float2(m2[mt][j], lsum[mt][j]);
            }
    }
}

// ---------------------------------------------------------------------------
// Combine the two KV-split halves: out = (w0*O0 + w1*O1)/(w0+w1), bf16.
// w_z = l_z * exp2(m_z - max(m0,m1)).  One block per row (4096), 256 thr.
// ---------------------------------------------------------------------------
__global__ __launch_bounds__(256) void attn_comb(const ushort* __restrict__ Opart,
                                                 const float* __restrict__ ml,
                                                 ushort* __restrict__ outb) {
    int row = blockIdx.x;            // bb*T_ + t
    int tid = threadIdx.x;
    int col = tid * 4;
    int head = col >> 6;
    float2 ml0 = *(const float2*)(ml + ((size_t)head * BT_ + row) * 2);
    float2 ml1 = *(const float2*)(ml + ((size_t)(16 + head) * BT_ + row) * 2);
    float m = fmaxf(ml0.x, ml1.x);
    float w0 = ml0.y * __builtin_amdgcn_exp2f(ml0.x - m);
    float w1 = ml1.y * __builtin_amdgcn_exp2f(ml1.x - m);
    float inv = 1.0f / (w0 + w1);
    w0 *= inv; w1 *= inv;
    size_t idx = (size_t)row * C_ + col;
    ushort4 a = *(const ushort4*)(Opart + idx);
    ushort4 b = *(const ushort4*)(Opart + (size_t)BT_ * C_ + idx);
    ushort4 o;
    o.x = f2bf(bf2f(a.x) * w0 + bf2f(b.x) * w1);
    o.y = f2bf(bf2f(a.y) * w0 + bf2f(b.y) * w1);
    o.z = f2bf(bf2f(a.z) * w0 + bf2f(b.z) * w1);
    o.w = f2bf(bf2f(a.w) * w0 + bf2f(b.w) * w1);
    *(ushort4*)(outb + idx) = o;
}

// ---------------------------------------------------------------------------
extern "C" void kernel_launch(void* const* d_in, const int* in_sizes, int n_in,
                              void* d_out, int out_size, void* d_ws, size_t ws_size,
                              hipStream_t stream) {
    const float* x   = (const float*)d_in[0];
    const float* Wq  = (const float*)d_in[1];
    const float* Wk  = (const float*)d_in[2];
    const float* Wv  = (const float*)d_in[3];
    const float* Wo  = (const float*)d_in[4];
    const float* bo  = (const float*)d_in[5];
    const float* W1  = (const float*)d_in[6];
    const float* b1  = (const float*)d_in[7];
    const float* W2  = (const float*)d_in[8];
    const float* b2  = (const float*)d_in[9];
    const float* g1  = (const float*)d_in[10];
    const float* be1 = (const float*)d_in[11];
    const float* g2  = (const float*)d_in[12];
    const float* be2 = (const float*)d_in[13];
    float* out = (float*)d_out;

    char* ws = (char*)d_ws;
    const size_t MB = 1 << 20;
    ushort* h_bf    = (ushort*)(ws);                 // 8 MB
    ushort* qk_act  = (ushort*)(ws + 8*MB);          // 16 MB [4096][2048]
    ushort* vt      = (ushort*)(ws + 24*MB);         // 8 MB  [1024][4096] V^T
    ushort* attn_bf = (ushort*)(ws + 32*MB);         // 8 MB  [4096][1024]
    ushort* ff1     = (ushort*)(ws + 8*MB);          // 32 MB (reuses qk/vt/attn)
    ushort* qkvw    = (ushort*)(ws + 40*MB);         // 6 MB  [3072][1024]
    ushort* Wo_t    = (ushort*)(ws + 46*MB);         // 2 MB
    ushort* W1_t    = (ushort*)(ws + 48*MB);         // 8 MB
    ushort* W2_t    = (ushort*)(ws + 56*MB);         // 8 MB
    ushort* p01     = (ushort*)(ws + 40*MB);         // 16 MB bf16 FF2 partials
    ushort* Opart   = (ushort*)(ws + 64*MB);         // 16 MB [2][4096][1024] bf16
    float*  mlbuf   = (float*)(ws + 80*MB);          // 1 MB  [2][16][4096][2]

    const float* Wsrc[3] = {Wq, Wk, Wv};
    for (int w = 0; w < 3; w++) {
        tcvt_kernel<<<dim3(2, 32, 16), dim3(32, 8), 0, stream>>>(
            Wsrc[w], qkvw + (size_t)w * 1024 * 1024,
            1024, 64, 1024, 65536L, 65536L);
    }
    tcvt_kernel<<<dim3(32, 32, 1), dim3(32, 8), 0, stream>>>(
        Wo, Wo_t, 1024, 1024, 1024, 0L, 0L);
    tcvt_kernel<<<dim3(128, 32, 1), dim3(32, 8), 0, stream>>>(
        W1, W1_t, 1024, 4096, 1024, 0L, 0L);
    tcvt_kernel<<<dim3(32, 128, 1), dim3(32, 8), 0, stream>>>(
        W2, W2_t, 4096, 1024, 4096, 0L, 0L);

    // 1) h = LN(x) -> bf16
    ln_kernel<<<dim3(BT_), dim3(256), 0, stream>>>(x, g1, be1, h_bf);

    // 2a) qk = h @ [Wq|Wk]^T   [4096][2048]
    gemm2<0, true><<<dim3(2048/256, BT_/128, 1), dim3(512), 0, stream>>>(
        h_bf, qkvw, qk_act, nullptr, nullptr, BT_, 2048, C_, C_);
    // 2b) vt = Wv^T @ h^T -> V^T [1024][4096]
    gemm2<0, true><<<dim3(BT_/256, 1024/128, 1), dim3(512), 0, stream>>>(
        qkvw + (size_t)2*1024*1024, h_bf, vt, nullptr, nullptr, 1024, BT_, C_, C_);

    // 3) attention: direct-from-global, KV-parity split, then combine
    attn_mfma<<<dim3(16, B_*H_, 2), dim3(256), 0, stream>>>(qk_act, vt, Opart, mlbuf);
    attn_comb<<<dim3(BT_), dim3(256), 0, stream>>>(Opart, mlbuf, attn_bf);

    // 4) out = x + attn @ Wo + bo  (fp32)
    gemm2<1|4, false><<<dim3(1024/256, BT_/128, 1), dim3(512), 0, stream>>>(
        attn_bf, Wo_t, out, bo, x, BT_, C_, C_, C_);

    // 5) h2 = LN(out) -> bf16
    ln_kernel<<<dim3(BT_), dim3(256), 0, stream>>>(out, g2, be2, h_bf);

    // 6) ff1 = relu(h2 @ W1 + b1) -> bf16
    gemm2<1|2, true><<<dim3(FF_/256, BT_/128, 1), dim3(512), 0, stream>>>(
        h_bf, W1_t, ff1, b1, nullptr, BT_, FF_, C_, C_);

    // 7) FF2 split-K=2: partials (bf16), then out += p0 + p1 + b2
    gemm2<0, true><<<dim3(1024/256, BT_/128, 2), dim3(512), 0, stream>>>(
        ff1, W2_t, p01, nullptr, nullptr, BT_, C_, FF_, 2048);
    ff2_red<<<dim3(BT_*C_/4/256), dim3(256), 0, stream>>>(out, p01, b2);
}

// Round 11
// 325.652 us; speedup vs baseline: 1.2941x; 1.2941x over previous
//
#include <hip/hip_runtime.h>
#include <hip/hip_bf16.h>
#include <cstdint>
#include <cstddef>
#include <cstring>

#define B_ 2
#define T_ 2048
#define C_ 1024
#define H_ 16
#define HD_ 64
#define FF_ 4096
#define BT_ (B_*T_)   // 4096 rows

typedef __attribute__((ext_vector_type(8))) short short8;
typedef __attribute__((ext_vector_type(4))) float f32x4;

__device__ __forceinline__ float bf2f(ushort u) {
    return __uint_as_float(((uint)u) << 16);
}
__device__ __forceinline__ ushort f2bf(float f) {
    uint x = __float_as_uint(f);
    return (ushort)((x + 0x7fffu + ((x >> 16) & 1u)) >> 16);
}
// hot-path convert: scalar cast so compiler can fuse v_cvt_pk_bf16_f32 (m240)
__device__ __forceinline__ ushort f2bf_hw(float f) {
    __hip_bfloat16 h = __float2bfloat16(f);
    ushort u;
    __builtin_memcpy(&u, &h, 2);
    return u;
}

#define GLDS16(g, l)                                                        \
    __builtin_amdgcn_global_load_lds(                                       \
        (const __attribute__((address_space(1))) void*)(g),                 \
        (__attribute__((address_space(3))) void*)(l), 16, 0, 0)

// ---------------------------------------------------------------------------
// LayerNorm: one block (256 threads) per row of C_=1024, fp32 in, bf16 out.
// ---------------------------------------------------------------------------
__global__ __launch_bounds__(256) void ln_kernel(const float* __restrict__ x,
                                                 const float* __restrict__ g,
                                                 const float* __restrict__ b,
                                                 ushort* __restrict__ out) {
    int row = blockIdx.x;
    int tid = threadIdx.x;
    const float* xr = x + (size_t)row * C_;
    float4 v = *(const float4*)(xr + tid * 4);
    float s = v.x + v.y + v.z + v.w;
    float q = v.x*v.x + v.y*v.y + v.z*v.z + v.w*v.w;
    #pragma unroll
    for (int off = 32; off > 0; off >>= 1) {
        s += __shfl_down(s, off);
        q += __shfl_down(q, off);
    }
    __shared__ float ss[4], qs[4];
    if ((tid & 63) == 0) { ss[tid >> 6] = s; qs[tid >> 6] = q; }
    __syncthreads();
    s = ss[0] + ss[1] + ss[2] + ss[3];
    q = qs[0] + qs[1] + qs[2] + qs[3];
    float mu  = s * (1.0f / C_);
    float var = q * (1.0f / C_) - mu * mu;
    float r = rsqrtf(var + 1e-5f);
    float4 gv = *(const float4*)(g + tid * 4);
    float4 bv = *(const float4*)(b + tid * 4);
    ushort4 o;
    o.x = f2bf((v.x - mu) * r * gv.x + bv.x);
    o.y = f2bf((v.y - mu) * r * gv.y + bv.y);
    o.z = f2bf((v.z - mu) * r * gv.z + bv.z);
    o.w = f2bf((v.w - mu) * r * gv.w + bv.w);
    *(ushort4*)(out + (size_t)row * C_ + tid * 4) = o;
}

// ---------------------------------------------------------------------------
// Tiled transpose + fp32->bf16 convert. (weights, once per call)
// ---------------------------------------------------------------------------
__global__ __launch_bounds__(256) void tcvt_kernel(const float* __restrict__ in,
                                                   ushort* __restrict__ out,
                                                   int R, int Cc, int ldo,
                                                   long in_bs, long out_bs) {
    __shared__ float tile[32][33];
    const float* inz = in + (size_t)blockIdx.z * in_bs;
    ushort* outz = out + (size_t)blockIdx.z * out_bs;
    int c0 = blockIdx.x * 32, r0 = blockIdx.y * 32;
    #pragma unroll
    for (int i = 0; i < 4; i++) {
        int r = threadIdx.y + i * 8;
        tile[r][threadIdx.x] = inz[(size_t)(r0 + r) * Cc + c0 + threadIdx.x];
    }
    __syncthreads();
    #pragma unroll
    for (int i = 0; i < 4; i++) {
        int c = threadIdx.y + i * 8;
        outz[(size_t)(c0 + c) * ldo + r0 + threadIdx.x] = f2bf(tile[threadIdx.x][c]);
    }
}

// ---------------------------------------------------------------------------
// bf16 MFMA GEMM, phase-structured (T2+T3+T4+T5+T1):
// BM=128 x BN=256, BK=64, 512 thr = 8 waves. (unchanged from round 7)
// ---------------------------------------------------------------------------
template<int EPI, bool OUT_BF16>
__global__ __launch_bounds__(512, 2) void gemm2(
    const ushort* __restrict__ A,
    const ushort* __restrict__ Bt,
    void* __restrict__ Cout,
    const float* __restrict__ bias,
    const float* __restrict__ resid,
    int M, int N, int K, int KS)
{
    __shared__ ushort As[2][128 * 64];   // 2 x 16 KB
    __shared__ ushort Bs[2][256 * 64];   // 2 x 32 KB

    int gx = gridDim.x;
    int nwg = gx * gridDim.y;
    int bid = blockIdx.y * gx + blockIdx.x;
    int cpx = nwg >> 3;
    int swz = (bid & 7) * cpx + (bid >> 3);
    int bx = swz % gx, by = swz / gx;

    int tid  = threadIdx.x;
    int lane = tid & 63;
    int lr = lane & 15, lq = lane >> 4;
    int wave = tid >> 6;                 // 0..7
    int wr = wave >> 2, wc = wave & 3;
    int m0 = by * 128, n0 = bx * 256;
    int Koff = blockIdx.z * KS;
    size_t zoff = (size_t)blockIdx.z * ((size_t)M * N);

    f32x4 acc[4][4];
    #pragma unroll
    for (int i = 0; i < 4; i++)
        #pragma unroll
        for (int j = 0; j < 4; j++)
            acc[i][j] = {0.f, 0.f, 0.f, 0.f};

    int srow = tid >> 3;
    int scol = ((tid & 7) ^ (srow & 7)) * 8;
    const ushort* gA = A  + (size_t)(m0 + srow) * K + Koff + scol;
    const ushort* gB = Bt + (size_t)(n0 + srow) * K + Koff + scol;
    int NT = KS / 64;

    auto stage = [&](int kt, int buf) {
        const ushort* a = gA + kt * 64;
        const ushort* b = gB + kt * 64;
        char* la = (char*)As[buf] + wave * 1024;
        char* lb = (char*)Bs[buf] + wave * 1024;
        GLDS16(a, la);
        GLDS16(a + (size_t)64 * K, la + 8192);
        #pragma unroll
        for (int i = 0; i < 4; i++)
            GLDS16(b + (size_t)i * 64 * K, lb + i * 8192);
    };

    stage(0, 0);
    stage(1, 1);
    asm volatile("s_waitcnt vmcnt(6)" ::: "memory");
    __builtin_amdgcn_s_barrier();

    int sx4 = (lr & 7) << 4;
    int so0 = (lq << 4) ^ sx4;
    int so1 = ((4 + lq) << 4) ^ sx4;

    int cur = 0;
    for (int t = 0; t < NT; ++t) {
        const char* Ab = (const char*)As[cur] + (wr * 64 + lr) * 128;
        const char* Bb = (const char*)Bs[cur] + (wc * 64 + lr) * 128;

        short8 bf[4][2], af[2][2];
        #pragma unroll
        for (int fc = 0; fc < 4; fc++) {
            bf[fc][0] = *(const short8*)(Bb + fc * 2048 + so0);
            bf[fc][1] = *(const short8*)(Bb + fc * 2048 + so1);
        }
        #pragma unroll
        for (int r = 0; r < 2; r++) {
            af[r][0] = *(const short8*)(Ab + r * 2048 + so0);
            af[r][1] = *(const short8*)(Ab + r * 2048 + so1);
        }
        __builtin_amdgcn_s_barrier();
        __builtin_amdgcn_s_setprio(1);
        #pragma unroll
        for (int r = 0; r < 2; r++)
            #pragma unroll
            for (int fc = 0; fc < 4; fc++) {
                acc[r][fc] = __builtin_amdgcn_mfma_f32_16x16x32_bf16(
                    af[r][0], bf[fc][0], acc[r][fc], 0, 0, 0);
                acc[r][fc] = __builtin_amdgcn_mfma_f32_16x16x32_bf16(
                    af[r][1], bf[fc][1], acc[r][fc], 0, 0, 0);
            }
        __builtin_amdgcn_s_setprio(0);
        __builtin_amdgcn_s_barrier();

        #pragma unroll
        for (int r = 0; r < 2; r++) {
            af[r][0] = *(const short8*)(Ab + (2 + r) * 2048 + so0);
            af[r][1] = *(const short8*)(Ab + (2 + r) * 2048 + so1);
        }
        __builtin_amdgcn_s_barrier();
        __builtin_amdgcn_s_setprio(1);
        #pragma unroll
        for (int r = 0; r < 2; r++)
            #pragma unroll
            for (int fc = 0; fc < 4; fc++) {
                acc[2 + r][fc] = __builtin_amdgcn_mfma_f32_16x16x32_bf16(
                    af[r][0], bf[fc][0], acc[2 + r][fc], 0, 0, 0);
                acc[2 + r][fc] = __builtin_amdgcn_mfma_f32_16x16x32_bf16(
                    af[r][1], bf[fc][1], acc[2 + r][fc], 0, 0, 0);
            }
        __builtin_amdgcn_s_setprio(0);
        __builtin_amdgcn_s_barrier();

        if (t + 1 == NT) break;
        if (t + 2 < NT) {
            stage(t + 2, cur);
            asm volatile("s_waitcnt vmcnt(6)" ::: "memory");
        } else {
            asm volatile("s_waitcnt vmcnt(0)" ::: "memory");
        }
        __builtin_amdgcn_s_barrier();
        cur ^= 1;
    }

    #pragma unroll
    for (int fr = 0; fr < 4; fr++) {
        #pragma unroll
        for (int fc = 0; fc < 4; fc++) {
            int col = n0 + wc * 64 + fc * 16 + lr;
            #pragma unroll
            for (int j = 0; j < 4; j++) {
                int row = m0 + wr * 64 + fr * 16 + lq * 4 + j;
                float v = acc[fr][fc][j];
                if (EPI & 1) v += bias[col];
                if (EPI & 2) v = fmaxf(v, 0.f);
                if (EPI & 4) v += resid[(size_t)row * N + col];
                if (OUT_BF16)
                    ((ushort*)Cout)[zoff + (size_t)row * N + col] = f2bf(v);
                else
                    ((float*)Cout)[zoff + (size_t)row * N + col] = v;
            }
        }
    }
}

// ---------------------------------------------------------------------------
// FF2 split-K finalize: out += p0 + p1 + b2   (p bf16 partials, out fp32)
// ---------------------------------------------------------------------------
__global__ __launch_bounds__(256) void ff2_red(float* __restrict__ out,
                                               const ushort* __restrict__ p,
                                               const float* __restrict__ b2) {
    size_t i = (size_t)blockIdx.x * 256 + threadIdx.x;   // 4-elem groups
    float4 o = ((float4*)out)[i];
    ushort4 a = ((const ushort4*)p)[i];
    ushort4 b = ((const ushort4*)(p + (size_t)BT_ * C_))[i];
    float4 c = ((const float4*)b2)[i & 255];
    o.x += bf2f(a.x) + bf2f(b.x) + c.x;
    o.y += bf2f(a.y) + bf2f(b.y) + c.y;
    o.z += bf2f(a.z) + bf2f(b.z) + c.z;
    o.w += bf2f(a.w) + bf2f(b.w) + c.w;
    ((float4*)out)[i] = o;
}

// ---------------------------------------------------------------------------
// Wo split-K finalize: out = x + p0 + p1 + bo   (fresh write, fp32)
// ---------------------------------------------------------------------------
__global__ __launch_bounds__(256) void wo_red(float* __restrict__ out,
                                              const ushort* __restrict__ p,
                                              const float* __restrict__ bo,
                                              const float* __restrict__ x) {
    size_t i = (size_t)blockIdx.x * 256 + threadIdx.x;   // 4-elem groups
    float4 o = ((const float4*)x)[i];
    ushort4 a = ((const ushort4*)p)[i];
    ushort4 b = ((const ushort4*)(p + (size_t)BT_ * C_))[i];
    float4 c = ((const float4*)bo)[i & 255];
    o.x += bf2f(a.x) + bf2f(b.x) + c.x;
    o.y += bf2f(a.y) + bf2f(b.y) + c.y;
    o.z += bf2f(a.z) + bf2f(b.z) + c.z;
    o.w += bf2f(a.w) + bf2f(b.w) + c.w;
    ((float4*)out)[i] = o;
}

// ---------------------------------------------------------------------------
// MFMA causal flash attention: KVBLK=64 double-buffered staging + KV-parity
// split.  LDS = 48 KB (Ks 2x8 + Vs 2x8 + Ps 16) -> 3 blocks/CU; grid has
// 1024 blocks -> ~12 waves/CU (vs 8 at the 80 KB config) for latency hiding.
// Compute body identical to the verified R7 kernel (64-key halves).
// qk : [BT_][2048] bf16 (q at h*64, k at 1024+h*64)
// vt : [1024][4096] bf16 = V^T;  Opart: [2][BT_][1024] bf16
// ml : [2][H][BT_][2] fp32  (m2 log2-domain, l)
// ---------------------------------------------------------------------------
__global__ __launch_bounds__(256, 3) void attn_mfma(const ushort* __restrict__ qk,
                                                    const ushort* __restrict__ vt,
                                                    ushort* __restrict__ Opart,
                                                    float* __restrict__ ml) {
    const float C2 = 0.18033688011f;     // 0.125 * log2(e)
    const float THR2 = 12.0f;            // defer-max threshold (log2 domain)

    int bh = blockIdx.y;
    int bb = bh >> 4;
    int head = bh & 15;
    int qa = 15 - blockIdx.x;            // heavy tiles first
    int q0 = qa * 128;
    int z = blockIdx.z;

    int tid  = threadIdx.x;
    int lane = tid & 63;
    int lr = lane & 15, lq = lane >> 4;
    int wave = tid >> 6;
    int qw = q0 + wave * 32;

    __shared__ ushort Ks[2][64 * 64];    // 2 x 8 KB [key][d], swizzled slots
    __shared__ ushort Vs[2][64 * 64];    // 2 x 8 KB [d][key], swizzled
    __shared__ ushort Ps[4][32 * 64];    // 16 KB per-wave P, swizzled
    char* pw = (char*)Ps[wave];

    short8 qf[2][2];
    {
        const ushort* qb = qk + ((size_t)(bb * T_ + qw)) * 2048 + head * 64;
        #pragma unroll
        for (int mt = 0; mt < 2; mt++)
            #pragma unroll
            for (int kk = 0; kk < 2; kk++)
                qf[mt][kk] = *(const short8*)(qb + (size_t)(mt*16 + lr) * 2048 + kk*32 + lq*8);
    }

    f32x4 acc[2][4];
    f32x4 lsum[2];
    float m2[2][4];
    #pragma unroll
    for (int mt = 0; mt < 2; mt++) {
        #pragma unroll
        for (int dt = 0; dt < 4; dt++) acc[mt][dt] = {0.f, 0.f, 0.f, 0.f};
        lsum[mt] = {0.f, 0.f, 0.f, 0.f};
        #pragma unroll
        for (int j = 0; j < 4; j++) m2[mt][j] = -INFINITY;
    }

    const short8 onesf = {(short)0x3F80, (short)0x3F80, (short)0x3F80, (short)0x3F80,
                          (short)0x3F80, (short)0x3F80, (short)0x3F80, (short)0x3F80};

    // staging geometry: thread covers K/V row tid>>3 (+32 on 2nd issue),
    // 16B slot tid&7; source col pre-swizzled, LDS linear (T21 discipline).
    int srow = tid >> 3;                 // 0..31
    int ssc = ((tid & 7) ^ (srow & 7)) * 8;
    const ushort* kg0 = qk + ((size_t)(bb * T_ + srow)) * 2048 + 1024 + head * 64 + ssc;
    const ushort* vg0 = vt + ((size_t)(head * 64 + srow)) * 4096 + (size_t)bb * 2048 + ssc;

    auto stage = [&](int it, int buf) {
        int s0 = it * 64;
        char* Kb = (char*)Ks[buf] + wave * 1024;
        char* Vb = (char*)Vs[buf] + wave * 1024;
        GLDS16(kg0 + (size_t)s0 * 2048,        Kb);
        GLDS16(kg0 + (size_t)(s0 + 32) * 2048, Kb + 4096);
        GLDS16(vg0 + s0,                        Vb);
        GLDS16(vg0 + (size_t)32 * 4096 + s0,    Vb + 4096);
    };

    int nt = 2 * (qa + 1);               // 64-key tiles for this q-tile
    stage(z, 0);
    __syncthreads();
    int cur = 0;

    for (int it = z; it < nt; it += 2) {
        if (it + 2 < nt) stage(it + 2, cur ^ 1);

        int s0h = it * 64;
        if (s0h <= qw + 31) {            // wave-uniform causal skip
            const ushort* Kc = Ks[cur];
            const ushort* Vc = Vs[cur];

            // ---- S = Q K^T ----
            f32x4 sa[2][4];
            __builtin_amdgcn_s_setprio(1);
            #pragma unroll
            for (int n = 0; n < 4; n++) {
                int row = n*16 + lr;
                const char* kbase = (const char*)Kc + row*128;
                short8 kf0 = *(const short8*)(kbase + ((lq       ^ (row & 7)) << 4));
                short8 kf1 = *(const short8*)(kbase + (((4 + lq) ^ (row & 7)) << 4));
                #pragma unroll
                for (int mt = 0; mt < 2; mt++) {
                    f32x4 tq = {0.f, 0.f, 0.f, 0.f};
                    tq = __builtin_amdgcn_mfma_f32_16x16x32_bf16(qf[mt][0], kf0, tq, 0, 0, 0);
                    tq = __builtin_amdgcn_mfma_f32_16x16x32_bf16(qf[mt][1], kf1, tq, 0, 0, 0);
                    sa[mt][n] = tq;
                }
            }
            __builtin_amdgcn_s_setprio(0);

            // ---- causal mask (diagonal tile only; wave-uniform branch) ----
            if (s0h + 63 > qw) {
                #pragma unroll
                for (int mt = 0; mt < 2; mt++)
                    #pragma unroll
                    for (int n = 0; n < 4; n++)
                        #pragma unroll
                        for (int j = 0; j < 4; j++) {
                            int scolm = s0h + n*16 + lr;
                            int qrow = qw + mt*16 + lq*4 + j;
                            if (scolm > qrow) sa[mt][n][j] = -INFINITY;
                        }
            }

            // ---- row maxes (log2-scaled) + defer-max vote ----
            float vmax2[2][4];
            bool growf = false;
            #pragma unroll
            for (int mt = 0; mt < 2; mt++) {
                #pragma unroll
                for (int j = 0; j < 4; j++) {
                    float v = fmaxf(fmaxf(sa[mt][0][j], sa[mt][1][j]),
                                    fmaxf(sa[mt][2][j], sa[mt][3][j]));
                    #pragma unroll
                    for (int off = 1; off < 16; off <<= 1)
                        v = fmaxf(v, __shfl_xor(v, off));
                    float v2 = v * C2;
                    vmax2[mt][j] = v2;
                    growf |= (v2 > m2[mt][j] + THR2);
                }
            }
            if (__any(growf)) {
                #pragma unroll
                for (int mt = 0; mt < 2; mt++)
                    #pragma unroll
                    for (int j = 0; j < 4; j++) {
                        float m2n = fmaxf(m2[mt][j], vmax2[mt][j]);
                        float corr = __builtin_amdgcn_exp2f(m2[mt][j] - m2n);
                        m2[mt][j] = m2n;
                        lsum[mt][j] *= corr;
                        #pragma unroll
                        for (int dt = 0; dt < 4; dt++)
                            acc[mt][dt][j] *= corr;
                    }
            }

            // ---- P = exp2(s*C2 - m2) -> bf16 -> per-wave swizzled LDS ----
            #pragma unroll
            for (int mt = 0; mt < 2; mt++)
                #pragma unroll
                for (int n = 0; n < 4; n++)
                    #pragma unroll
                    for (int j = 0; j < 4; j++) {
                        float p = __builtin_amdgcn_exp2f(
                            fmaf(sa[mt][n][j], C2, -m2[mt][j]));
                        int row = mt*16 + lq*4 + j;
                        int col = n*16 + lr;
                        int byte = row*128 + ((((col >> 3) ^ (row & 7))) << 4) + (col & 7)*2;
                        *(ushort*)(pw + byte) = f2bf_hw(p);
                    }

            // ---- read P fragments; lsum += P*1; O += P V ----
            short8 pf[2][2];
            #pragma unroll
            for (int mt = 0; mt < 2; mt++) {
                int row = mt*16 + lr;
                #pragma unroll
                for (int kk = 0; kk < 2; kk++)
                    pf[mt][kk] = *(const short8*)(pw + row*128
                                   + (((kk*4 + lq) ^ (row & 7)) << 4));
            }
            __builtin_amdgcn_s_setprio(1);
            #pragma unroll
            for (int kk = 0; kk < 2; kk++)
                #pragma unroll
                for (int mt = 0; mt < 2; mt++)
                    lsum[mt] = __builtin_amdgcn_mfma_f32_16x16x32_bf16(
                        pf[mt][kk], onesf, lsum[mt], 0, 0, 0);
            #pragma unroll
            for (int dt = 0; dt < 4; dt++) {
                int row = dt*16 + lr;
                const char* vbase = (const char*)Vc + row*128;
                #pragma unroll
                for (int kk = 0; kk < 2; kk++) {
                    short8 vf = *(const short8*)(vbase
                                  + (((kk*4 + lq) ^ (row & 7)) << 4));
                    #pragma unroll
                    for (int mt = 0; mt < 2; mt++)
                        acc[mt][dt] = __builtin_amdgcn_mfma_f32_16x16x32_bf16(
                            pf[mt][kk], vf, acc[mt][dt], 0, 0, 0);
                }
            }
            __builtin_amdgcn_s_setprio(0);
        }

        __syncthreads();   // all waves done with buf[cur]; prefetch drained
        cur ^= 1;
    }

    // ---- epilogue: normalized partial O -> Opart[z]; (m2,l) -> ml ----
    ushort* ob = Opart + (size_t)z * ((size_t)BT_ * C_)
               + ((size_t)(bb * T_ + qw)) * 1024 + head * 64;
    #pragma unroll
    for (int mt = 0; mt < 2; mt++)
        #pragma unroll
        for (int j = 0; j < 4; j++) {
            float l = lsum[mt][j];
            float inv = l > 0.f ? 1.0f / l : 0.f;
            #pragma unroll
            for (int dt = 0; dt < 4; dt++)
                ob[(size_t)(mt*16 + lq*4 + j) * 1024 + dt*16 + lr] =
                    f2bf(acc[mt][dt][j] * inv);
        }
    if (lr == 0) {
        float* mlz = ml + ((size_t)(z * 16 + head)) * (BT_ * 2);
        #pragma unroll
        for (int mt = 0; mt < 2; mt++)
            #pragma unroll
            for (int j = 0; j < 4; j++) {
                size_t row = (size_t)(bb * T_ + qw + mt*16 + lq*4 + j);
                *(float2*)(mlz + row * 2) = make_float2(m2[mt][j], lsum[mt][j]);
            }
    }
}

// ---------------------------------------------------------------------------
// Combine the two KV-split halves: out = (w0*O0 + w1*O1)/(w0+w1), bf16.
// w_z = l_z * exp2(m_z - max(m0,m1)).  One block per row (4096), 256 thr.
// ---------------------------------------------------------------------------
__global__ __launch_bounds__(256) void attn_comb(const ushort* __restrict__ Opart,
                                                 const float* __restrict__ ml,
                                                 ushort* __restrict__ outb) {
    int row = blockIdx.x;            // bb*T_ + t
    int tid = threadIdx.x;
    int col = tid * 4;
    int head = col >> 6;
    float2 ml0 = *(const float2*)(ml + ((size_t)head * BT_ + row) * 2);
    float2 ml1 = *(const float2*)(ml + ((size_t)(16 + head) * BT_ + row) * 2);
    float m = fmaxf(ml0.x, ml1.x);
    float w0 = ml0.y * __builtin_amdgcn_exp2f(ml0.x - m);
    float w1 = ml1.y * __builtin_amdgcn_exp2f(ml1.x - m);
    float inv = 1.0f / (w0 + w1);
    w0 *= inv; w1 *= inv;
    size_t idx = (size_t)row * C_ + col;
    ushort4 a = *(const ushort4*)(Opart + idx);
    ushort4 b = *(const ushort4*)(Opart + (size_t)BT_ * C_ + idx);
    ushort4 o;
    o.x = f2bf(bf2f(a.x) * w0 + bf2f(b.x) * w1);
    o.y = f2bf(bf2f(a.y) * w0 + bf2f(b.y) * w1);
    o.z = f2bf(bf2f(a.z) * w0 + bf2f(b.z) * w1);
    o.w = f2bf(bf2f(a.w) * w0 + bf2f(b.w) * w1);
    *(ushort4*)(outb + idx) = o;
}

// ---------------------------------------------------------------------------
extern "C" void kernel_launch(void* const* d_in, const int* in_sizes, int n_in,
                              void* d_out, int out_size, void* d_ws, size_t ws_size,
                              hipStream_t stream) {
    const float* x   = (const float*)d_in[0];
    const float* Wq  = (const float*)d_in[1];
    const float* Wk  = (const float*)d_in[2];
    const float* Wv  = (const float*)d_in[3];
    const float* Wo  = (const float*)d_in[4];
    const float* bo  = (const float*)d_in[5];
    const float* W1  = (const float*)d_in[6];
    const float* b1  = (const float*)d_in[7];
    const float* W2  = (const float*)d_in[8];
    const float* b2  = (const float*)d_in[9];
    const float* g1  = (const float*)d_in[10];
    const float* be1 = (const float*)d_in[11];
    const float* g2  = (const float*)d_in[12];
    const float* be2 = (const float*)d_in[13];
    float* out = (float*)d_out;

    char* ws = (char*)d_ws;
    const size_t MB = 1 << 20;
    ushort* h_bf    = (ushort*)(ws);                 // 8 MB
    ushort* qk_act  = (ushort*)(ws + 8*MB);          // 16 MB [4096][2048]
    ushort* vt      = (ushort*)(ws + 24*MB);         // 8 MB  [1024][4096] V^T
    ushort* attn_bf = (ushort*)(ws + 32*MB);         // 8 MB  [4096][1024]
    ushort* ff1     = (ushort*)(ws + 8*MB);          // 32 MB (reuses qk/vt/attn)
    ushort* p_wo    = (ushort*)(ws + 8*MB);          // 16 MB Wo partials (qk_act dead)
    ushort* qkvw    = (ushort*)(ws + 40*MB);         // 6 MB  [3072][1024]
    ushort* Wo_t    = (ushort*)(ws + 46*MB);         // 2 MB
    ushort* W1_t    = (ushort*)(ws + 48*MB);         // 8 MB
    ushort* W2_t    = (ushort*)(ws + 56*MB);         // 8 MB
    ushort* p01     = (ushort*)(ws + 40*MB);         // 16 MB FF2 partials (weights dead)
    ushort* Opart   = (ushort*)(ws + 64*MB);         // 16 MB [2][4096][1024] bf16
    float*  mlbuf   = (float*)(ws + 80*MB);          // 1 MB  [2][16][4096][2]

    const float* Wsrc[3] = {Wq, Wk, Wv};
    for (int w = 0; w < 3; w++) {
        tcvt_kernel<<<dim3(2, 32, 16), dim3(32, 8), 0, stream>>>(
            Wsrc[w], qkvw + (size_t)w * 1024 * 1024,
            1024, 64, 1024, 65536L, 65536L);
    }
    tcvt_kernel<<<dim3(32, 32, 1), dim3(32, 8), 0, stream>>>(
        Wo, Wo_t, 1024, 1024, 1024, 0L, 0L);
    tcvt_kernel<<<dim3(128, 32, 1), dim3(32, 8), 0, stream>>>(
        W1, W1_t, 1024, 4096, 1024, 0L, 0L);
    tcvt_kernel<<<dim3(32, 128, 1), dim3(32, 8), 0, stream>>>(
        W2, W2_t, 4096, 1024, 4096, 0L, 0L);

    // 1) h = LN(x) -> bf16
    ln_kernel<<<dim3(BT_), dim3(256), 0, stream>>>(x, g1, be1, h_bf);

    // 2a) qk = h @ [Wq|Wk]^T   [4096][2048]
    gemm2<0, true><<<dim3(2048/256, BT_/128, 1), dim3(512), 0, stream>>>(
        h_bf, qkvw, qk_act, nullptr, nullptr, BT_, 2048, C_, C_);
    // 2b) vt = Wv^T @ h^T -> V^T [1024][4096]
    gemm2<0, true><<<dim3(BT_/256, 1024/128, 1), dim3(512), 0, stream>>>(
        qkvw + (size_t)2*1024*1024, h_bf, vt, nullptr, nullptr, 1024, BT_, C_, C_);

    // 3) attention: KVBLK=64 dbuf, KV-parity split (1024 blocks), combine
    attn_mfma<<<dim3(16, B_*H_, 2), dim3(256), 0, stream>>>(qk_act, vt, Opart, mlbuf);
    attn_comb<<<dim3(BT_), dim3(256), 0, stream>>>(Opart, mlbuf, attn_bf);

    // 4) Wo split-K=2 (256 wg): partials, then out = x + p0 + p1 + bo
    gemm2<0, true><<<dim3(1024/256, BT_/128, 2), dim3(512), 0, stream>>>(
        attn_bf, Wo_t, p_wo, nullptr, nullptr, BT_, C_, C_, 512);
    wo_red<<<dim3(BT_*C_/4/256), dim3(256), 0, stream>>>(out, p_wo, bo, x);

    // 5) h2 = LN(out) -> bf16
    ln_kernel<<<dim3(BT_), dim3(256), 0, stream>>>(out, g2, be2, h_bf);

    // 6) ff1 = relu(h2 @ W1 + b1) -> bf16
    gemm2<1|2, true><<<dim3(FF_/256, BT_/128, 1), dim3(512), 0, stream>>>(
        h_bf, W1_t, ff1, b1, nullptr, BT_, FF_, C_, C_);

    // 7) FF2 split-K=2: partials (bf16), then out += p0 + p1 + b2
    gemm2<0, true><<<dim3(1024/256, BT_/128, 2), dim3(512), 0, stream>>>(
        ff1, W2_t, p01, nullptr, nullptr, BT_, C_, FF_, 2048);
    ff2_red<<<dim3(BT_*C_/4/256), dim3(256), 0, stream>>>(out, p01, b2);
}

// Round 12
// 306.360 us; speedup vs baseline: 1.3756x; 1.0630x over previous
//
#include <hip/hip_runtime.h>
#include <hip/hip_bf16.h>
#include <cstdint>
#include <cstddef>
#include <cstring>

#define B_ 2
#define T_ 2048
#define C_ 1024
#define H_ 16
#define HD_ 64
#define FF_ 4096
#define BT_ (B_*T_)   // 4096 rows

typedef __attribute__((ext_vector_type(8))) short short8;
typedef __attribute__((ext_vector_type(4))) float f32x4;

__device__ __forceinline__ float bf2f(ushort u) {
    return __uint_as_float(((uint)u) << 16);
}
__device__ __forceinline__ ushort f2bf(float f) {
    uint x = __float_as_uint(f);
    return (ushort)((x + 0x7fffu + ((x >> 16) & 1u)) >> 16);
}
// hot-path convert: scalar cast so compiler can fuse v_cvt_pk_bf16_f32 (m240)
__device__ __forceinline__ ushort f2bf_hw(float f) {
    __hip_bfloat16 h = __float2bfloat16(f);
    ushort u;
    __builtin_memcpy(&u, &h, 2);
    return u;
}

#define GLDS16(g, l)                                                        \
    __builtin_amdgcn_global_load_lds(                                       \
        (const __attribute__((address_space(1))) void*)(g),                 \
        (__attribute__((address_space(3))) void*)(l), 16, 0, 0)

// ---------------------------------------------------------------------------
// LayerNorm: one block (256 threads) per row of C_=1024, fp32 in, bf16 out.
// ---------------------------------------------------------------------------
__global__ __launch_bounds__(256) void ln_kernel(const float* __restrict__ x,
                                                 const float* __restrict__ g,
                                                 const float* __restrict__ b,
                                                 ushort* __restrict__ out) {
    int row = blockIdx.x;
    int tid = threadIdx.x;
    const float* xr = x + (size_t)row * C_;
    float4 v = *(const float4*)(xr + tid * 4);
    float s = v.x + v.y + v.z + v.w;
    float q = v.x*v.x + v.y*v.y + v.z*v.z + v.w*v.w;
    #pragma unroll
    for (int off = 32; off > 0; off >>= 1) {
        s += __shfl_down(s, off);
        q += __shfl_down(q, off);
    }
    __shared__ float ss[4], qs[4];
    if ((tid & 63) == 0) { ss[tid >> 6] = s; qs[tid >> 6] = q; }
    __syncthreads();
    s = ss[0] + ss[1] + ss[2] + ss[3];
    q = qs[0] + qs[1] + qs[2] + qs[3];
    float mu  = s * (1.0f / C_);
    float var = q * (1.0f / C_) - mu * mu;
    float r = rsqrtf(var + 1e-5f);
    float4 gv = *(const float4*)(g + tid * 4);
    float4 bv = *(const float4*)(b + tid * 4);
    ushort4 o;
    o.x = f2bf((v.x - mu) * r * gv.x + bv.x);
    o.y = f2bf((v.y - mu) * r * gv.y + bv.y);
    o.z = f2bf((v.z - mu) * r * gv.z + bv.z);
    o.w = f2bf((v.w - mu) * r * gv.w + bv.w);
    *(ushort4*)(out + (size_t)row * C_ + tid * 4) = o;
}

// ---------------------------------------------------------------------------
// Tiled transpose + fp32->bf16 convert. (weights, once per call)
// ---------------------------------------------------------------------------
__global__ __launch_bounds__(256) void tcvt_kernel(const float* __restrict__ in,
                                                   ushort* __restrict__ out,
                                                   int R, int Cc, int ldo,
                                                   long in_bs, long out_bs) {
    __shared__ float tile[32][33];
    const float* inz = in + (size_t)blockIdx.z * in_bs;
    ushort* outz = out + (size_t)blockIdx.z * out_bs;
    int c0 = blockIdx.x * 32, r0 = blockIdx.y * 32;
    #pragma unroll
    for (int i = 0; i < 4; i++) {
        int r = threadIdx.y + i * 8;
        tile[r][threadIdx.x] = inz[(size_t)(r0 + r) * Cc + c0 + threadIdx.x];
    }
    __syncthreads();
    #pragma unroll
    for (int i = 0; i < 4; i++) {
        int c = threadIdx.y + i * 8;
        outz[(size_t)(c0 + c) * ldo + r0 + threadIdx.x] = f2bf(tile[threadIdx.x][c]);
    }
}

// ---------------------------------------------------------------------------
// bf16 MFMA GEMM: BM=128 x BN=256, BK=32, 512 thr = 8 waves (2Mr x 4Nc).
// LDS 48 KB (2x8 A + 2x16 B dbuf) -> 2-3 blocks/CU; VGPR capped via
// __launch_bounds__(512,4) -> 16 waves/CU (2x the 96 KB config).
// 2-deep prefetch with counted vmcnt(3) (never drain-0 mid-loop); raw
// s_barriers; lgkmcnt(0)+sched_barrier pin before releasing the buffer
// (rule 18).  BK=32 swizzle: slot = lq ^ ((row>>1)&3), inverse on source.
// A [M][K] bf16, Bt [N][K] bf16. EPI: 1=bias, 2=relu, 4=residual fp32.
// Split-K via gridDim.z: Koff = z*KS, output z-slab at Cout + z*M*N.
// ---------------------------------------------------------------------------
template<int EPI, bool OUT_BF16>
__global__ __launch_bounds__(512, 4) void gemm2(
    const ushort* __restrict__ A,
    const ushort* __restrict__ Bt,
    void* __restrict__ Cout,
    const float* __restrict__ bias,
    const float* __restrict__ resid,
    int M, int N, int K, int KS)
{
    __shared__ ushort As[2][128 * 32];   // 2 x 8 KB
    __shared__ ushort Bs[2][256 * 32];   // 2 x 16 KB

    // T1: bijective XCD swizzle (nwg % 8 == 0 at all call sites)
    int gx = gridDim.x;
    int nwg = gx * gridDim.y;
    int bid = blockIdx.y * gx + blockIdx.x;
    int cpx = nwg >> 3;
    int swz = (bid & 7) * cpx + (bid >> 3);
    int bx = swz % gx, by = swz / gx;

    int tid  = threadIdx.x;
    int lane = tid & 63;
    int lr = lane & 15, lq = lane >> 4;
    int wave = tid >> 6;                 // 0..7
    int wr = wave >> 2, wc = wave & 3;
    int m0 = by * 128, n0 = bx * 256;
    int Koff = blockIdx.z * KS;
    size_t zoff = (size_t)blockIdx.z * ((size_t)M * N);

    f32x4 acc[4][4];
    #pragma unroll
    for (int i = 0; i < 4; i++)
        #pragma unroll
        for (int j = 0; j < 4; j++)
            acc[i][j] = {0.f, 0.f, 0.f, 0.f};

    // staging: thread covers row tid>>2, 16B slot tid&3 (linear LDS dest =
    // wave*1024 + lane*16); source col pre-swizzled: data[r][s^((r>>1)&3)]
    int srow = tid >> 2;                 // 0..127
    int scol = ((tid & 3) ^ ((srow >> 1) & 3)) * 8;
    const ushort* gA  = A  + (size_t)(m0 + srow) * K + Koff + scol;
    const ushort* gB0 = Bt + (size_t)(n0 + srow) * K + Koff + scol;
    const ushort* gB1 = Bt + (size_t)(n0 + 128 + srow) * K + Koff + scol;
    int NT = KS / 32;

    auto stage = [&](int kt, int buf) {
        int off = kt * 32;
        GLDS16(gA + off,  (char*)As[buf] + wave * 1024);
        GLDS16(gB0 + off, (char*)Bs[buf] + wave * 1024);
        GLDS16(gB1 + off, (char*)Bs[buf] + 8192 + wave * 1024);
    };

    stage(0, 0);
    stage(1, 1);
    asm volatile("s_waitcnt vmcnt(3)" ::: "memory");   // tile 0 landed
    __builtin_amdgcn_s_barrier();

    int so = (lq ^ ((lr >> 1) & 3)) << 4;   // fr-invariant read swizzle

    int cur = 0;
    for (int t = 0; t < NT; ++t) {
        const char* Ab = (const char*)As[cur] + (wr * 64 + lr) * 64 + so;
        const char* Bb = (const char*)Bs[cur] + (wc * 64 + lr) * 64 + so;

        short8 a[4], b[4];
        #pragma unroll
        for (int fr = 0; fr < 4; fr++)
            a[fr] = *(const short8*)(Ab + fr * 1024);
        #pragma unroll
        for (int fc = 0; fc < 4; fc++)
            b[fc] = *(const short8*)(Bb + fc * 1024);
        asm volatile("s_waitcnt lgkmcnt(0)" ::: "memory");  // frags in regs
        __builtin_amdgcn_sched_barrier(0);                  // rule 18 pin
        __builtin_amdgcn_s_barrier();      // all waves done reading buf[cur]

        if (t + 2 < NT) stage(t + 2, cur); // overwrite just-freed buffer

        __builtin_amdgcn_s_setprio(1);
        #pragma unroll
        for (int fr = 0; fr < 4; fr++)
            #pragma unroll
            for (int fc = 0; fc < 4; fc++)
                acc[fr][fc] = __builtin_amdgcn_mfma_f32_16x16x32_bf16(
                    a[fr], b[fc], acc[fr][fc], 0, 0, 0);
        __builtin_amdgcn_s_setprio(0);

        if (t + 1 == NT) break;
        if (t + 2 < NT)
            asm volatile("s_waitcnt vmcnt(3)" ::: "memory");  // t+1 landed
        else
            asm volatile("s_waitcnt vmcnt(0)" ::: "memory");
        __builtin_amdgcn_s_barrier();
        cur ^= 1;
    }

    // ---- epilogue ----
    #pragma unroll
    for (int fr = 0; fr < 4; fr++) {
        #pragma unroll
        for (int fc = 0; fc < 4; fc++) {
            int col = n0 + wc * 64 + fc * 16 + lr;
            #pragma unroll
            for (int j = 0; j < 4; j++) {
                int row = m0 + wr * 64 + fr * 16 + lq * 4 + j;
                float v = acc[fr][fc][j];
                if (EPI & 1) v += bias[col];
                if (EPI & 2) v = fmaxf(v, 0.f);
                if (EPI & 4) v += resid[(size_t)row * N + col];
                if (OUT_BF16)
                    ((ushort*)Cout)[zoff + (size_t)row * N + col] = f2bf(v);
                else
                    ((float*)Cout)[zoff + (size_t)row * N + col] = v;
            }
        }
    }
}

// ---------------------------------------------------------------------------
// FF2 split-K finalize: out += p0 + p1 + b2   (p bf16 partials, out fp32)
// ---------------------------------------------------------------------------
__global__ __launch_bounds__(256) void ff2_red(float* __restrict__ out,
                                               const ushort* __restrict__ p,
                                               const float* __restrict__ b2) {
    size_t i = (size_t)blockIdx.x * 256 + threadIdx.x;   // 4-elem groups
    float4 o = ((float4*)out)[i];
    ushort4 a = ((const ushort4*)p)[i];
    ushort4 b = ((const ushort4*)(p + (size_t)BT_ * C_))[i];
    float4 c = ((const float4*)b2)[i & 255];
    o.x += bf2f(a.x) + bf2f(b.x) + c.x;
    o.y += bf2f(a.y) + bf2f(b.y) + c.y;
    o.z += bf2f(a.z) + bf2f(b.z) + c.z;
    o.w += bf2f(a.w) + bf2f(b.w) + c.w;
    ((float4*)out)[i] = o;
}

// ---------------------------------------------------------------------------
// Wo split-K finalize: out = x + p0 + p1 + bo   (fresh write, fp32)
// ---------------------------------------------------------------------------
__global__ __launch_bounds__(256) void wo_red(float* __restrict__ out,
                                              const ushort* __restrict__ p,
                                              const float* __restrict__ bo,
                                              const float* __restrict__ x) {
    size_t i = (size_t)blockIdx.x * 256 + threadIdx.x;   // 4-elem groups
    float4 o = ((const float4*)x)[i];
    ushort4 a = ((const ushort4*)p)[i];
    ushort4 b = ((const ushort4*)(p + (size_t)BT_ * C_))[i];
    float4 c = ((const float4*)bo)[i & 255];
    o.x += bf2f(a.x) + bf2f(b.x) + c.x;
    o.y += bf2f(a.y) + bf2f(b.y) + c.y;
    o.z += bf2f(a.z) + bf2f(b.z) + c.z;
    o.w += bf2f(a.w) + bf2f(b.w) + c.w;
    ((float4*)out)[i] = o;
}

// ---------------------------------------------------------------------------
// MFMA causal flash attention: KVBLK=64 double-buffered staging + KV-parity
// split.  LDS = 48 KB -> 3 blocks/CU; grid 1024 blocks. (unchanged from R11)
// qk : [BT_][2048] bf16 (q at h*64, k at 1024+h*64)
// vt : [1024][4096] bf16 = V^T;  Opart: [2][BT_][1024] bf16
// ml : [2][H][BT_][2] fp32  (m2 log2-domain, l)
// ---------------------------------------------------------------------------
__global__ __launch_bounds__(256, 3) void attn_mfma(const ushort* __restrict__ qk,
                                                    const ushort* __restrict__ vt,
                                                    ushort* __restrict__ Opart,
                                                    float* __restrict__ ml) {
    const float C2 = 0.18033688011f;     // 0.125 * log2(e)
    const float THR2 = 12.0f;            // defer-max threshold (log2 domain)

    int bh = blockIdx.y;
    int bb = bh >> 4;
    int head = bh & 15;
    int qa = 15 - blockIdx.x;            // heavy tiles first
    int q0 = qa * 128;
    int z = blockIdx.z;

    int tid  = threadIdx.x;
    int lane = tid & 63;
    int lr = lane & 15, lq = lane >> 4;
    int wave = tid >> 6;
    int qw = q0 + wave * 32;

    __shared__ ushort Ks[2][64 * 64];    // 2 x 8 KB [key][d], swizzled slots
    __shared__ ushort Vs[2][64 * 64];    // 2 x 8 KB [d][key], swizzled
    __shared__ ushort Ps[4][32 * 64];    // 16 KB per-wave P, swizzled
    char* pw = (char*)Ps[wave];

    short8 qf[2][2];
    {
        const ushort* qb = qk + ((size_t)(bb * T_ + qw)) * 2048 + head * 64;
        #pragma unroll
        for (int mt = 0; mt < 2; mt++)
            #pragma unroll
            for (int kk = 0; kk < 2; kk++)
                qf[mt][kk] = *(const short8*)(qb + (size_t)(mt*16 + lr) * 2048 + kk*32 + lq*8);
    }

    f32x4 acc[2][4];
    f32x4 lsum[2];
    float m2[2][4];
    #pragma unroll
    for (int mt = 0; mt < 2; mt++) {
        #pragma unroll
        for (int dt = 0; dt < 4; dt++) acc[mt][dt] = {0.f, 0.f, 0.f, 0.f};
        lsum[mt] = {0.f, 0.f, 0.f, 0.f};
        #pragma unroll
        for (int j = 0; j < 4; j++) m2[mt][j] = -INFINITY;
    }

    const short8 onesf = {(short)0x3F80, (short)0x3F80, (short)0x3F80, (short)0x3F80,
                          (short)0x3F80, (short)0x3F80, (short)0x3F80, (short)0x3F80};

    int srow = tid >> 3;                 // 0..31
    int ssc = ((tid & 7) ^ (srow & 7)) * 8;
    const ushort* kg0 = qk + ((size_t)(bb * T_ + srow)) * 2048 + 1024 + head * 64 + ssc;
    const ushort* vg0 = vt + ((size_t)(head * 64 + srow)) * 4096 + (size_t)bb * 2048 + ssc;

    auto stage = [&](int it, int buf) {
        int s0 = it * 64;
        char* Kb = (char*)Ks[buf] + wave * 1024;
        char* Vb = (char*)Vs[buf] + wave * 1024;
        GLDS16(kg0 + (size_t)s0 * 2048,        Kb);
        GLDS16(kg0 + (size_t)(s0 + 32) * 2048, Kb + 4096);
        GLDS16(vg0 + s0,                        Vb);
        GLDS16(vg0 + (size_t)32 * 4096 + s0,    Vb + 4096);
    };

    int nt = 2 * (qa + 1);               // 64-key tiles for this q-tile
    stage(z, 0);
    __syncthreads();
    int cur = 0;

    for (int it = z; it < nt; it += 2) {
        if (it + 2 < nt) stage(it + 2, cur ^ 1);

        int s0h = it * 64;
        if (s0h <= qw + 31) {            // wave-uniform causal skip
            const ushort* Kc = Ks[cur];
            const ushort* Vc = Vs[cur];

            // ---- S = Q K^T ----
            f32x4 sa[2][4];
            __builtin_amdgcn_s_setprio(1);
            #pragma unroll
            for (int n = 0; n < 4; n++) {
                int row = n*16 + lr;
                const char* kbase = (const char*)Kc + row*128;
                short8 kf0 = *(const short8*)(kbase + ((lq       ^ (row & 7)) << 4));
                short8 kf1 = *(const short8*)(kbase + (((4 + lq) ^ (row & 7)) << 4));
                #pragma unroll
                for (int mt = 0; mt < 2; mt++) {
                    f32x4 tq = {0.f, 0.f, 0.f, 0.f};
                    tq = __builtin_amdgcn_mfma_f32_16x16x32_bf16(qf[mt][0], kf0, tq, 0, 0, 0);
                    tq = __builtin_amdgcn_mfma_f32_16x16x32_bf16(qf[mt][1], kf1, tq, 0, 0, 0);
                    sa[mt][n] = tq;
                }
            }
            __builtin_amdgcn_s_setprio(0);

            // ---- causal mask (diagonal tile only; wave-uniform branch) ----
            if (s0h + 63 > qw) {
                #pragma unroll
                for (int mt = 0; mt < 2; mt++)
                    #pragma unroll
                    for (int n = 0; n < 4; n++)
                        #pragma unroll
                        for (int j = 0; j < 4; j++) {
                            int scolm = s0h + n*16 + lr;
                            int qrow = qw + mt*16 + lq*4 + j;
                            if (scolm > qrow) sa[mt][n][j] = -INFINITY;
                        }
            }

            // ---- row maxes (log2-scaled) + defer-max vote ----
            float vmax2[2][4];
            bool growf = false;
            #pragma unroll
            for (int mt = 0; mt < 2; mt++) {
                #pragma unroll
                for (int j = 0; j < 4; j++) {
                    float v = fmaxf(fmaxf(sa[mt][0][j], sa[mt][1][j]),
                                    fmaxf(sa[mt][2][j], sa[mt][3][j]));
                    #pragma unroll
                    for (int off = 1; off < 16; off <<= 1)
                        v = fmaxf(v, __shfl_xor(v, off));
                    float v2 = v * C2;
                    vmax2[mt][j] = v2;
                    growf |= (v2 > m2[mt][j] + THR2);
                }
            }
            if (__any(growf)) {
                #pragma unroll
                for (int mt = 0; mt < 2; mt++)
                    #pragma unroll
                    for (int j = 0; j < 4; j++) {
                        float m2n = fmaxf(m2[mt][j], vmax2[mt][j]);
                        float corr = __builtin_amdgcn_exp2f(m2[mt][j] - m2n);
                        m2[mt][j] = m2n;
                        lsum[mt][j] *= corr;
                        #pragma unroll
                        for (int dt = 0; dt < 4; dt++)
                            acc[mt][dt][j] *= corr;
                    }
            }

            // ---- P = exp2(s*C2 - m2) -> bf16 -> per-wave swizzled LDS ----
            #pragma unroll
            for (int mt = 0; mt < 2; mt++)
                #pragma unroll
                for (int n = 0; n < 4; n++)
                    #pragma unroll
                    for (int j = 0; j < 4; j++) {
                        float p = __builtin_amdgcn_exp2f(
                            fmaf(sa[mt][n][j], C2, -m2[mt][j]));
                        int row = mt*16 + lq*4 + j;
                        int col = n*16 + lr;
                        int byte = row*128 + ((((col >> 3) ^ (row & 7))) << 4) + (col & 7)*2;
                        *(ushort*)(pw + byte) = f2bf_hw(p);
                    }

            // ---- read P fragments; lsum += P*1; O += P V ----
            short8 pf[2][2];
            #pragma unroll
            for (int mt = 0; mt < 2; mt++) {
                int row = mt*16 + lr;
                #pragma unroll
                for (int kk = 0; kk < 2; kk++)
                    pf[mt][kk] = *(const short8*)(pw + row*128
                                   + (((kk*4 + lq) ^ (row & 7)) << 4));
            }
            __builtin_amdgcn_s_setprio(1);
            #pragma unroll
            for (int kk = 0; kk < 2; kk++)
                #pragma unroll
                for (int mt = 0; mt < 2; mt++)
                    lsum[mt] = __builtin_amdgcn_mfma_f32_16x16x32_bf16(
                        pf[mt][kk], onesf, lsum[mt], 0, 0, 0);
            #pragma unroll
            for (int dt = 0; dt < 4; dt++) {
                int row = dt*16 + lr;
                const char* vbase = (const char*)Vc + row*128;
                #pragma unroll
                for (int kk = 0; kk < 2; kk++) {
                    short8 vf = *(const short8*)(vbase
                                  + (((kk*4 + lq) ^ (row & 7)) << 4));
                    #pragma unroll
                    for (int mt = 0; mt < 2; mt++)
                        acc[mt][dt] = __builtin_amdgcn_mfma_f32_16x16x32_bf16(
                            pf[mt][kk], vf, acc[mt][dt], 0, 0, 0);
                }
            }
            __builtin_amdgcn_s_setprio(0);
        }

        __syncthreads();   // all waves done with buf[cur]; prefetch drained
        cur ^= 1;
    }

    // ---- epilogue: normalized partial O -> Opart[z]; (m2,l) -> ml ----
    ushort* ob = Opart + (size_t)z * ((size_t)BT_ * C_)
               + ((size_t)(bb * T_ + qw)) * 1024 + head * 64;
    #pragma unroll
    for (int mt = 0; mt < 2; mt++)
        #pragma unroll
        for (int j = 0; j < 4; j++) {
            float l = lsum[mt][j];
            float inv = l > 0.f ? 1.0f / l : 0.f;
            #pragma unroll
            for (int dt = 0; dt < 4; dt++)
                ob[(size_t)(mt*16 + lq*4 + j) * 1024 + dt*16 + lr] =
                    f2bf(acc[mt][dt][j] * inv);
        }
    if (lr == 0) {
        float* mlz = ml + ((size_t)(z * 16 + head)) * (BT_ * 2);
        #pragma unroll
        for (int mt = 0; mt < 2; mt++)
            #pragma unroll
            for (int j = 0; j < 4; j++) {
                size_t row = (size_t)(bb * T_ + qw + mt*16 + lq*4 + j);
                *(float2*)(mlz + row * 2) = make_float2(m2[mt][j], lsum[mt][j]);
            }
    }
}

// ---------------------------------------------------------------------------
// Combine the two KV-split halves: out = (w0*O0 + w1*O1)/(w0+w1), bf16.
// ---------------------------------------------------------------------------
__global__ __launch_bounds__(256) void attn_comb(const ushort* __restrict__ Opart,
                                                 const float* __restrict__ ml,
                                                 ushort* __restrict__ outb) {
    int row = blockIdx.x;            // bb*T_ + t
    int tid = threadIdx.x;
    int col = tid * 4;
    int head = col >> 6;
    float2 ml0 = *(const float2*)(ml + ((size_t)head * BT_ + row) * 2);
    float2 ml1 = *(const float2*)(ml + ((size_t)(16 + head) * BT_ + row) * 2);
    float m = fmaxf(ml0.x, ml1.x);
    float w0 = ml0.y * __builtin_amdgcn_exp2f(ml0.x - m);
    float w1 = ml1.y * __builtin_amdgcn_exp2f(ml1.x - m);
    float inv = 1.0f / (w0 + w1);
    w0 *= inv; w1 *= inv;
    size_t idx = (size_t)row * C_ + col;
    ushort4 a = *(const ushort4*)(Opart + idx);
    ushort4 b = *(const ushort4*)(Opart + (size_t)BT_ * C_ + idx);
    ushort4 o;
    o.x = f2bf(bf2f(a.x) * w0 + bf2f(b.x) * w1);
    o.y = f2bf(bf2f(a.y) * w0 + bf2f(b.y) * w1);
    o.z = f2bf(bf2f(a.z) * w0 + bf2f(b.z) * w1);
    o.w = f2bf(bf2f(a.w) * w0 + bf2f(b.w) * w1);
    *(ushort4*)(outb + idx) = o;
}

// ---------------------------------------------------------------------------
extern "C" void kernel_launch(void* const* d_in, const int* in_sizes, int n_in,
                              void* d_out, int out_size, void* d_ws, size_t ws_size,
                              hipStream_t stream) {
    const float* x   = (const float*)d_in[0];
    const float* Wq  = (const float*)d_in[1];
    const float* Wk  = (const float*)d_in[2];
    const float* Wv  = (const float*)d_in[3];
    const float* Wo  = (const float*)d_in[4];
    const float* bo  = (const float*)d_in[5];
    const float* W1  = (const float*)d_in[6];
    const float* b1  = (const float*)d_in[7];
    const float* W2  = (const float*)d_in[8];
    const float* b2  = (const float*)d_in[9];
    const float* g1  = (const float*)d_in[10];
    const float* be1 = (const float*)d_in[11];
    const float* g2  = (const float*)d_in[12];
    const float* be2 = (const float*)d_in[13];
    float* out = (float*)d_out;

    char* ws = (char*)d_ws;
    const size_t MB = 1 << 20;
    ushort* h_bf    = (ushort*)(ws);                 // 8 MB
    ushort* qk_act  = (ushort*)(ws + 8*MB);          // 16 MB [4096][2048]
    ushort* vt      = (ushort*)(ws + 24*MB);         // 8 MB  [1024][4096] V^T
    ushort* attn_bf = (ushort*)(ws + 32*MB);         // 8 MB  [4096][1024]
    ushort* ff1     = (ushort*)(ws + 8*MB);          // 32 MB (reuses qk/vt/attn)
    ushort* p_wo    = (ushort*)(ws + 8*MB);          // 16 MB Wo partials (qk_act dead)
    ushort* qkvw    = (ushort*)(ws + 40*MB);         // 6 MB  [3072][1024]
    ushort* Wo_t    = (ushort*)(ws + 46*MB);         // 2 MB
    ushort* W1_t    = (ushort*)(ws + 48*MB);         // 8 MB
    ushort* W2_t    = (ushort*)(ws + 56*MB);         // 8 MB
    ushort* p01     = (ushort*)(ws + 40*MB);         // 16 MB FF2 partials (weights dead)
    ushort* Opart   = (ushort*)(ws + 64*MB);         // 16 MB [2][4096][1024] bf16
    float*  mlbuf   = (float*)(ws + 80*MB);          // 1 MB  [2][16][4096][2]

    const float* Wsrc[3] = {Wq, Wk, Wv};
    for (int w = 0; w < 3; w++) {
        tcvt_kernel<<<dim3(2, 32, 16), dim3(32, 8), 0, stream>>>(
            Wsrc[w], qkvw + (size_t)w * 1024 * 1024,
            1024, 64, 1024, 65536L, 65536L);
    }
    tcvt_kernel<<<dim3(32, 32, 1), dim3(32, 8), 0, stream>>>(
        Wo, Wo_t, 1024, 1024, 1024, 0L, 0L);
    tcvt_kernel<<<dim3(128, 32, 1), dim3(32, 8), 0, stream>>>(
        W1, W1_t, 1024, 4096, 1024, 0L, 0L);
    tcvt_kernel<<<dim3(32, 128, 1), dim3(32, 8), 0, stream>>>(
        W2, W2_t, 4096, 1024, 4096, 0L, 0L);

    // 1) h = LN(x) -> bf16
    ln_kernel<<<dim3(BT_), dim3(256), 0, stream>>>(x, g1, be1, h_bf);

    // 2a) qk = h @ [Wq|Wk]^T   [4096][2048]   grid 8x32 = 256 wg
    gemm2<0, true><<<dim3(2048/256, BT_/128, 1), dim3(512), 0, stream>>>(
        h_bf, qkvw, qk_act, nullptr, nullptr, BT_, 2048, C_, C_);
    // 2b) vt = Wv^T @ h^T -> V^T [1024][4096]  grid 16x8 = 128 wg
    gemm2<0, true><<<dim3(BT_/256, 1024/128, 1), dim3(512), 0, stream>>>(
        qkvw + (size_t)2*1024*1024, h_bf, vt, nullptr, nullptr, 1024, BT_, C_, C_);

    // 3) attention: KVBLK=64 dbuf, KV-parity split (1024 blocks), combine
    attn_mfma<<<dim3(16, B_*H_, 2), dim3(256), 0, stream>>>(qk_act, vt, Opart, mlbuf);
    attn_comb<<<dim3(BT_), dim3(256), 0, stream>>>(Opart, mlbuf, attn_bf);

    // 4) Wo split-K=2 (256 wg): partials, then out = x + p0 + p1 + bo
    gemm2<0, true><<<dim3(1024/256, BT_/128, 2), dim3(512), 0, stream>>>(
        attn_bf, Wo_t, p_wo, nullptr, nullptr, BT_, C_, C_, 512);
    wo_red<<<dim3(BT_*C_/4/256), dim3(256), 0, stream>>>(out, p_wo, bo, x);

    // 5) h2 = LN(out) -> bf16
    ln_kernel<<<dim3(BT_), dim3(256), 0, stream>>>(out, g2, be2, h_bf);

    // 6) ff1 = relu(h2 @ W1 + b1) -> bf16   grid 16x32 = 512 wg
    gemm2<1|2, true><<<dim3(FF_/256, BT_/128, 1), dim3(512), 0, stream>>>(
        h_bf, W1_t, ff1, b1, nullptr, BT_, FF_, C_, C_);

    // 7) FF2 split-K=2: partials (bf16), then out += p0 + p1 + b2
    gemm2<0, true><<<dim3(1024/256, BT_/128, 2), dim3(512), 0, stream>>>(
        ff1, W2_t, p01, nullptr, nullptr, BT_, C_, FF_, 2048);
    ff2_red<<<dim3(BT_*C_/4/256), dim3(256), 0, stream>>>(out, p01, b2);
}